// Round 1
// baseline (442.384 us; speedup 1.0000x reference)
//
#include <hip/hip_runtime.h>

#define HWX (96*96)
#define CIN 64
#define COUT 64
#define NKK 9

// wT[kk][c][co] <- w[co][c][kk]
__global__ void dcn_transpose_weight(const float* __restrict__ w, float* __restrict__ wT) {
    int idx = blockIdx.x * blockDim.x + threadIdx.x; // 64*64*9 = 36864 threads exactly
    int kk = idx % 9;
    int c  = (idx / 9) % 64;
    int co = idx / (9 * 64);
    wT[(kk * 64 + c) * 64 + co] = w[idx];
}

__global__ __launch_bounds__(64) void dcn_fwd(const float* __restrict__ x,
                                              const float* __restrict__ offset,
                                              const float* __restrict__ mask,
                                              const float* __restrict__ wT,
                                              float* __restrict__ out) {
    int bid = blockIdx.x;
    // bijective XCD swizzle: 1152 blocks, 8 XCDs, 144 blocks per XCD chunk
    int swz = (bid & 7) * 144 + (bid >> 3);
    int pid = swz * 64 + threadIdx.x;
    int n   = pid / HWX;
    int rem = pid % HWX;
    int ho  = rem / 96;
    int wo  = rem % 96;

    const float* xn = x + n * (CIN * HWX);
    float acc[COUT];
    #pragma unroll
    for (int i = 0; i < COUT; ++i) acc[i] = 0.f;

    #pragma unroll 1
    for (int kk = 0; kk < NKK; ++kk) {
        int ky = kk / 3, kx = kk % 3;
        float dy = offset[((n * 18 + 2 * kk + 0) * 96 + ho) * 96 + wo];
        float dx = offset[((n * 18 + 2 * kk + 1) * 96 + ho) * 96 + wo];
        float m  = mask[((n * 9 + kk) * 96 + ho) * 96 + wo];

        float py = dy + (float)(ky + ho - 1);
        float px = dx + (float)(kx + wo - 1);
        float y0f = floorf(py), x0f = floorf(px);
        float wy1 = py - y0f,  wx1 = px - x0f;
        float wy0 = 1.f - wy1, wx0 = 1.f - wx1;
        int y0 = (int)y0f, x0 = (int)x0f;
        int y1 = y0 + 1,   x1 = x0 + 1;
        bool vy0 = (y0 >= 0) && (y0 < 96);
        bool vy1 = (y1 >= 0) && (y1 < 96);
        bool vx0 = (x0 >= 0) && (x0 < 96);
        bool vx1 = (x1 >= 0) && (x1 < 96);
        int y0c = min(max(y0, 0), 95), y1c = min(max(y1, 0), 95);
        int x0c = min(max(x0, 0), 95), x1c = min(max(x1, 0), 95);
        // fold validity and mask into corner weights (matches ref: v * (w * valid), then * m)
        float w00 = wy0 * wx0 * m * ((vy0 && vx0) ? 1.f : 0.f);
        float w01 = wy0 * wx1 * m * ((vy0 && vx1) ? 1.f : 0.f);
        float w10 = wy1 * wx0 * m * ((vy1 && vx0) ? 1.f : 0.f);
        float w11 = wy1 * wx1 * m * ((vy1 && vx1) ? 1.f : 0.f);

        int b00 = y0c * 96 + x0c;
        int b01 = y0c * 96 + x1c;
        int b10 = y1c * 96 + x0c;
        int b11 = y1c * 96 + x1c;

        const float* wrow = wT + kk * (64 * 64);

        // software prefetch of first sample set
        float n00 = xn[b00], n01 = xn[b01], n10 = xn[b10], n11 = xn[b11];

        #pragma unroll 1
        for (int c = 0; c < CIN; ++c) {
            float v00 = n00, v01 = n01, v10 = n10, v11 = n11;
            if (c < CIN - 1) {
                b00 += HWX; b01 += HWX; b10 += HWX; b11 += HWX;
                n00 = xn[b00]; n01 = xn[b01]; n10 = xn[b10]; n11 = xn[b11];
            }
            float s = w00 * v00 + w01 * v01 + w10 * v10 + w11 * v11;
            const float4* w4 = (const float4*)(wrow + c * 64); // uniform address -> s_load
            #pragma unroll
            for (int j = 0; j < 16; ++j) {
                float4 ww = w4[j];
                acc[4 * j + 0] = fmaf(s, ww.x, acc[4 * j + 0]);
                acc[4 * j + 1] = fmaf(s, ww.y, acc[4 * j + 1]);
                acc[4 * j + 2] = fmaf(s, ww.z, acc[4 * j + 2]);
                acc[4 * j + 3] = fmaf(s, ww.w, acc[4 * j + 3]);
            }
        }
    }

    float* outp = out + (size_t)n * COUT * HWX + ho * 96 + wo;
    #pragma unroll
    for (int co = 0; co < COUT; ++co) {
        outp[co * HWX] = acc[co];
    }
}

extern "C" void kernel_launch(void* const* d_in, const int* in_sizes, int n_in,
                              void* d_out, int out_size, void* d_ws, size_t ws_size,
                              hipStream_t stream) {
    const float* x      = (const float*)d_in[0];
    const float* offset = (const float*)d_in[1];
    const float* mask   = (const float*)d_in[2];
    const float* w      = (const float*)d_in[3];
    float* out = (float*)d_out;
    float* wT  = (float*)d_ws; // 36864 floats = 147456 B of scratch

    hipLaunchKernelGGL(dcn_transpose_weight, dim3(144), dim3(256), 0, stream, w, wT);
    hipLaunchKernelGGL(dcn_fwd, dim3(1152), dim3(64), 0, stream, x, offset, mask, wT, out);
}

// Round 2
// 158.927 us; speedup vs baseline: 2.7836x; 2.7836x over previous
//
#include <hip/hip_runtime.h>

#define HWX 9216
#define CIN 64
#define COUT 64

typedef __attribute__((ext_vector_type(8))) short short8;
typedef __attribute__((ext_vector_type(4))) float f32x4;

__device__ inline short f2bf(float f) {
    union { float f; unsigned u; } v; v.f = f;
    unsigned r = (v.u + 0x7FFFu + ((v.u >> 16) & 1u)) >> 16;  // RNE
    return (short)r;
}

// wA fragment layout: idx = ((step*4 + m0)*64 + lane)*8 + j
// holds W[co = m0*16 + (lane&15)][kg = step*32 + (lane>>4)*8 + j] as bf16,
// where kg = kk*64 + c  (kk = kg>>6, c = kg&63), W stored [co][c][kk].
__global__ void dcn_prep_weight(const float* __restrict__ w, short* __restrict__ wA) {
    int idx = blockIdx.x * blockDim.x + threadIdx.x;  // 36864 threads
    int j    = idx & 7;
    int lane = (idx >> 3) & 63;
    int m0   = (idx >> 9) & 3;
    int step = idx >> 11;                 // 0..17
    int co = m0 * 16 + (lane & 15);
    int kg = step * 32 + ((lane >> 4) << 3) + j;
    int kk = kg >> 6;
    int c  = kg & 63;
    wA[idx] = f2bf(w[(co * 64 + c) * 9 + kk]);
}

__global__ __launch_bounds__(256, 4) void dcn_fwd(const float* __restrict__ x,
                                                  const float* __restrict__ offset,
                                                  const float* __restrict__ mask,
                                                  const short* __restrict__ wA,
                                                  float* __restrict__ out) {
    int bid = blockIdx.x;
    // bijective XCD swizzle: 1152 blocks, 8 XCDs, 144 blocks/XCD; XCD q <-> image q
    int swz = (bid & 7) * 144 + (bid >> 3);

    int wave = threadIdx.x >> 6;
    int lane = threadIdx.x & 63;
    int l15  = lane & 15;      // pixel-in-group / D column
    int lg   = lane >> 4;      // 0..3: k-subgroup / D row-group

    int n    = swz / 144;                              // block-uniform (SGPR)
    int prem = (swz % 144) * 64 + wave * 16;           // wave's first pixel in image
    int ho   = prem / 96;
    int wo0  = prem % 96;                              // multiple of 16
    int wo   = wo0 + l15;

    const float* xn = x + n * (CIN * HWX);             // uniform base -> SGPR

    f32x4 acc[4] = {f32x4{0,0,0,0}, f32x4{0,0,0,0}, f32x4{0,0,0,0}, f32x4{0,0,0,0}};

    #pragma unroll 1
    for (int kk = 0; kk < 9; ++kk) {
        int ky = kk / 3, kx = kk % 3;
        float dy = offset[((n * 18 + 2 * kk + 0) * 96 + ho) * 96 + wo];
        float dx = offset[((n * 18 + 2 * kk + 1) * 96 + ho) * 96 + wo];
        float m  = mask[((n * 9 + kk) * 96 + ho) * 96 + wo];

        float py = dy + (float)(ky + ho - 1);
        float px = dx + (float)(kx + wo - 1);
        float y0f = floorf(py), x0f = floorf(px);
        float wy1 = py - y0f,  wx1 = px - x0f;
        float wy0 = 1.f - wy1, wx0 = 1.f - wx1;
        int y0 = (int)y0f, x0 = (int)x0f;
        int y1 = y0 + 1,   x1 = x0 + 1;
        bool vy0 = (y0 >= 0) && (y0 < 96);
        bool vy1 = (y1 >= 0) && (y1 < 96);
        bool vx0 = (x0 >= 0) && (x0 < 96);
        bool vx1 = (x1 >= 0) && (x1 < 96);
        int y0c = min(max(y0, 0), 95), y1c = min(max(y1, 0), 95);
        int x0c = min(max(x0, 0), 95), x1c = min(max(x1, 0), 95);
        float w00 = wy0 * wx0 * m * ((vy0 && vx0) ? 1.f : 0.f);
        float w01 = wy0 * wx1 * m * ((vy0 && vx1) ? 1.f : 0.f);
        float w10 = wy1 * wx0 * m * ((vy1 && vx0) ? 1.f : 0.f);
        float w11 = wy1 * wx1 * m * ((vy1 && vx1) ? 1.f : 0.f);
        int ib00 = y0c * 96 + x0c;
        int ib01 = y0c * 96 + x1c;
        int ib10 = y1c * 96 + x0c;
        int ib11 = y1c * 96 + x1c;

        #pragma unroll
        for (int half = 0; half < 2; ++half) {
            int step = kk * 2 + half;
            int cb   = half * 32 + lg * 8;  // this lane's first channel

            // A-fragments: coalesced 16B/lane, L1-hot (same 4KB for all waves this step)
            const short8* wp = (const short8*)wA + step * 256 + lane;
            short8 af0 = wp[0];
            short8 af1 = wp[64];
            short8 af2 = wp[128];
            short8 af3 = wp[192];

            // sample 8 channels for (pixel, kk) -> B fragment
            int o = cb * HWX;
            float s0, s1, s2, s3, s4, s5, s6, s7;
            #pragma unroll
            for (int j = 0; j < 8; ++j) {
                float v00 = xn[o + ib00];
                float v01 = xn[o + ib01];
                float v10 = xn[o + ib10];
                float v11 = xn[o + ib11];
                float s = w00 * v00 + w01 * v01 + w10 * v10 + w11 * v11;
                if (j == 0) s0 = s; else if (j == 1) s1 = s; else if (j == 2) s2 = s;
                else if (j == 3) s3 = s; else if (j == 4) s4 = s; else if (j == 5) s5 = s;
                else if (j == 6) s6 = s; else s7 = s;
                o += HWX;
            }
            short8 bfrag;
            bfrag[0] = f2bf(s0); bfrag[1] = f2bf(s1);
            bfrag[2] = f2bf(s2); bfrag[3] = f2bf(s3);
            bfrag[4] = f2bf(s4); bfrag[5] = f2bf(s5);
            bfrag[6] = f2bf(s6); bfrag[7] = f2bf(s7);

            acc[0] = __builtin_amdgcn_mfma_f32_16x16x32_bf16(af0, bfrag, acc[0], 0, 0, 0);
            acc[1] = __builtin_amdgcn_mfma_f32_16x16x32_bf16(af1, bfrag, acc[1], 0, 0, 0);
            acc[2] = __builtin_amdgcn_mfma_f32_16x16x32_bf16(af2, bfrag, acc[2], 0, 0, 0);
            acc[3] = __builtin_amdgcn_mfma_f32_16x16x32_bf16(af3, bfrag, acc[3], 0, 0, 0);
        }
    }

    // D layout: lane l, reg r -> row co = m0*16 + lg*4 + r, col pixel = l15
    size_t obase = (size_t)n * COUT * HWX + (size_t)ho * 96 + wo;
    #pragma unroll
    for (int m0 = 0; m0 < 4; ++m0) {
        #pragma unroll
        for (int r = 0; r < 4; ++r) {
            int co = m0 * 16 + lg * 4 + r;
            out[obase + (size_t)co * HWX] = acc[m0][r];
        }
    }
}

extern "C" void kernel_launch(void* const* d_in, const int* in_sizes, int n_in,
                              void* d_out, int out_size, void* d_ws, size_t ws_size,
                              hipStream_t stream) {
    const float* x      = (const float*)d_in[0];
    const float* offset = (const float*)d_in[1];
    const float* mask   = (const float*)d_in[2];
    const float* w      = (const float*)d_in[3];
    float* out = (float*)d_out;
    short* wA  = (short*)d_ws;  // 36864 shorts = 73728 B

    hipLaunchKernelGGL(dcn_prep_weight, dim3(144), dim3(256), 0, stream, w, wA);
    hipLaunchKernelGGL(dcn_fwd, dim3(1152), dim3(256), 0, stream, x, offset, mask, wA, out);
}

// Round 3
// 107.916 us; speedup vs baseline: 4.0993x; 1.4727x over previous
//
#include <hip/hip_runtime.h>

#define HWX 9216
#define CIN 64
#define COUT 64

typedef __attribute__((ext_vector_type(8))) short short8;
typedef __attribute__((ext_vector_type(4))) float f32x4;

__device__ inline short f2bf(float f) {
    union { float f; unsigned u; } v; v.f = f;
    unsigned r = (v.u + 0x7FFFu + ((v.u >> 16) & 1u)) >> 16;  // RNE
    return (short)r;
}

// NCHW -> NHWC: xt[n][pix][c] = x[n][c][pix]
__global__ __launch_bounds__(256) void nchw_to_nhwc(const float* __restrict__ x,
                                                    float* __restrict__ xt) {
    __shared__ float tile[64][65];
    int n  = blockIdx.x / 144;
    int p0 = (blockIdx.x % 144) * 64;
    const float* xp = x + (size_t)n * CIN * HWX + p0;
    #pragma unroll
    for (int it = 0; it < 16; ++it) {
        int px = threadIdx.x & 63;
        int c  = (threadIdx.x >> 6) + it * 4;
        tile[c][px] = xp[c * HWX + px];
    }
    __syncthreads();
    float* xo = xt + ((size_t)n * HWX + p0) * 64;
    #pragma unroll
    for (int it = 0; it < 16; ++it) {
        int c  = threadIdx.x & 63;
        int px = (threadIdx.x >> 6) + it * 4;
        xo[px * 64 + c] = tile[c][px];
    }
}

// wA fragment layout: idx = ((step*4 + m0)*64 + lane)*8 + j
__global__ void dcn_prep_weight(const float* __restrict__ w, short* __restrict__ wA) {
    int idx = blockIdx.x * blockDim.x + threadIdx.x;  // 36864 threads
    int j    = idx & 7;
    int lane = (idx >> 3) & 63;
    int m0   = (idx >> 9) & 3;
    int step = idx >> 11;
    int co = m0 * 16 + (lane & 15);
    int kg = step * 32 + ((lane >> 4) << 3) + j;
    int kk = kg >> 6;
    int c  = kg & 63;
    wA[idx] = f2bf(w[(co * 64 + c) * 9 + kk]);
}

__global__ __launch_bounds__(256, 4) void dcn_fwd(const float* __restrict__ xt,
                                                  const float* __restrict__ offset,
                                                  const float* __restrict__ mask,
                                                  const short* __restrict__ wA,
                                                  float* __restrict__ out) {
    int bid = blockIdx.x;
    int swz = (bid & 7) * 144 + (bid >> 3);

    int wave = threadIdx.x >> 6;
    int lane = threadIdx.x & 63;
    int l15  = lane & 15;
    int lg   = lane >> 4;

    int n    = swz / 144;
    int prem = (swz % 144) * 64 + wave * 16;
    int ho   = prem / 96;
    int wo0  = prem % 96;
    int wo   = wo0 + l15;

    const float* xn = xt + (size_t)n * HWX * 64;

    f32x4 acc[4] = {f32x4{0,0,0,0}, f32x4{0,0,0,0}, f32x4{0,0,0,0}, f32x4{0,0,0,0}};

    #pragma unroll 1
    for (int kk = 0; kk < 9; ++kk) {
        int ky = kk / 3, kx = kk % 3;
        float dy = offset[((n * 18 + 2 * kk + 0) * 96 + ho) * 96 + wo];
        float dx = offset[((n * 18 + 2 * kk + 1) * 96 + ho) * 96 + wo];
        float m  = mask[((n * 9 + kk) * 96 + ho) * 96 + wo];

        float py = dy + (float)(ky + ho - 1);
        float px = dx + (float)(kx + wo - 1);
        float y0f = floorf(py), x0f = floorf(px);
        float wy1 = py - y0f,  wx1 = px - x0f;
        float wy0 = 1.f - wy1, wx0 = 1.f - wx1;
        int y0 = (int)y0f, x0 = (int)x0f;
        int y1 = y0 + 1,   x1 = x0 + 1;
        bool vy0 = (y0 >= 0) && (y0 < 96);
        bool vy1 = (y1 >= 0) && (y1 < 96);
        bool vx0 = (x0 >= 0) && (x0 < 96);
        bool vx1 = (x1 >= 0) && (x1 < 96);
        int y0c = min(max(y0, 0), 95), y1c = min(max(y1, 0), 95);
        int x0c = min(max(x0, 0), 95), x1c = min(max(x1, 0), 95);
        float w00 = wy0 * wx0 * m * ((vy0 && vx0) ? 1.f : 0.f);
        float w01 = wy0 * wx1 * m * ((vy0 && vx1) ? 1.f : 0.f);
        float w10 = wy1 * wx0 * m * ((vy1 && vx0) ? 1.f : 0.f);
        float w11 = wy1 * wx1 * m * ((vy1 && vx1) ? 1.f : 0.f);
        int ib00 = (y0c * 96 + x0c) * 64;
        int ib01 = (y0c * 96 + x1c) * 64;
        int ib10 = (y1c * 96 + x0c) * 64;
        int ib11 = (y1c * 96 + x1c) * 64;

        #pragma unroll
        for (int half = 0; half < 2; ++half) {
            int step = kk * 2 + half;
            int cb   = half * 32 + lg * 8;

            const short8* wp = (const short8*)wA + step * 256 + lane;
            short8 af0 = wp[0];
            short8 af1 = wp[64];
            short8 af2 = wp[128];
            short8 af3 = wp[192];

            const float* xb = xn + cb;
            f32x4 c00a = *(const f32x4*)(xb + ib00), c00b = *(const f32x4*)(xb + ib00 + 4);
            f32x4 c01a = *(const f32x4*)(xb + ib01), c01b = *(const f32x4*)(xb + ib01 + 4);
            f32x4 c10a = *(const f32x4*)(xb + ib10), c10b = *(const f32x4*)(xb + ib10 + 4);
            f32x4 c11a = *(const f32x4*)(xb + ib11), c11b = *(const f32x4*)(xb + ib11 + 4);

            f32x4 sa = w00 * c00a + w01 * c01a + w10 * c10a + w11 * c11a;
            f32x4 sb = w00 * c00b + w01 * c01b + w10 * c10b + w11 * c11b;

            short8 bfrag;
            bfrag[0] = f2bf(sa[0]); bfrag[1] = f2bf(sa[1]);
            bfrag[2] = f2bf(sa[2]); bfrag[3] = f2bf(sa[3]);
            bfrag[4] = f2bf(sb[0]); bfrag[5] = f2bf(sb[1]);
            bfrag[6] = f2bf(sb[2]); bfrag[7] = f2bf(sb[3]);

            acc[0] = __builtin_amdgcn_mfma_f32_16x16x32_bf16(af0, bfrag, acc[0], 0, 0, 0);
            acc[1] = __builtin_amdgcn_mfma_f32_16x16x32_bf16(af1, bfrag, acc[1], 0, 0, 0);
            acc[2] = __builtin_amdgcn_mfma_f32_16x16x32_bf16(af2, bfrag, acc[2], 0, 0, 0);
            acc[3] = __builtin_amdgcn_mfma_f32_16x16x32_bf16(af3, bfrag, acc[3], 0, 0, 0);
        }
    }

    size_t obase = (size_t)n * COUT * HWX + (size_t)ho * 96 + wo;
    #pragma unroll
    for (int m0 = 0; m0 < 4; ++m0) {
        #pragma unroll
        for (int r = 0; r < 4; ++r) {
            int co = m0 * 16 + lg * 4 + r;
            out[obase + (size_t)co * HWX] = acc[m0][r];
        }
    }
}

extern "C" void kernel_launch(void* const* d_in, const int* in_sizes, int n_in,
                              void* d_out, int out_size, void* d_ws, size_t ws_size,
                              hipStream_t stream) {
    const float* x      = (const float*)d_in[0];
    const float* offset = (const float*)d_in[1];
    const float* mask   = (const float*)d_in[2];
    const float* w      = (const float*)d_in[3];
    float* out = (float*)d_out;
    float* xt  = (float*)d_ws;                                    // 18,874,368 B
    short* wA  = (short*)((char*)d_ws + (size_t)8 * HWX * 64 * 4); // +73,728 B

    hipLaunchKernelGGL(nchw_to_nhwc, dim3(1152), dim3(256), 0, stream, x, xt);
    hipLaunchKernelGGL(dcn_prep_weight, dim3(144), dim3(256), 0, stream, w, wA);
    hipLaunchKernelGGL(dcn_fwd, dim3(1152), dim3(256), 0, stream, xt, offset, mask, wA, out);
}

// Round 4
// 68.799 us; speedup vs baseline: 6.4301x; 1.5686x over previous
//
#include <hip/hip_runtime.h>

#define HWX 9216
#define CIN 64
#define COUT 64

typedef __attribute__((ext_vector_type(8))) short short8;
typedef __attribute__((ext_vector_type(4))) float f32x4;
typedef __attribute__((ext_vector_type(4))) unsigned int u32x4;

__device__ inline unsigned short f2bf(float f) {
    union { float f; unsigned u; } v; v.f = f;
    return (unsigned short)((v.u + 0x7FFFu + ((v.u >> 16) & 1u)) >> 16);  // RNE
}
__device__ inline unsigned pack2bf(float lo, float hi) {
    return (unsigned)f2bf(lo) | ((unsigned)f2bf(hi) << 16);
}
__device__ inline float u2f(unsigned u) {
    union { unsigned u; float f; } v; v.u = u; return v.f;
}

// NCHW f32 -> NHWC bf16 (packed 2 channels per u32)
__global__ __launch_bounds__(256) void nchw_to_nhwc_bf16(const float* __restrict__ x,
                                                         unsigned* __restrict__ xt) {
    __shared__ float tile[64][65];
    int n  = blockIdx.x / 144;
    int p0 = (blockIdx.x % 144) * 64;
    const float* xp = x + (size_t)n * CIN * HWX + p0;
    #pragma unroll
    for (int it = 0; it < 16; ++it) {
        int px = threadIdx.x & 63;
        int c  = (threadIdx.x >> 6) + it * 4;
        tile[c][px] = xp[c * HWX + px];
    }
    __syncthreads();
    unsigned* xo = xt + ((size_t)n * HWX + p0) * 32;   // 32 u32 (=64 bf16) per pixel
    #pragma unroll
    for (int it = 0; it < 8; ++it) {
        int c2 = threadIdx.x & 31;
        int px = (threadIdx.x >> 5) + it * 8;
        xo[px * 32 + c2] = pack2bf(tile[2 * c2][px], tile[2 * c2 + 1][px]);
    }
}

// wA fragment layout: idx = ((step*4 + m0)*64 + lane)*8 + j
// W[co = m0*16 + (lane&15)][kg = step*32 + (lane>>4)*8 + j], kg = kk*64 + c
__global__ void dcn_prep_weight(const float* __restrict__ w, short* __restrict__ wA) {
    int idx = blockIdx.x * blockDim.x + threadIdx.x;  // 36864 threads
    int j    = idx & 7;
    int lane = (idx >> 3) & 63;
    int m0   = (idx >> 9) & 3;
    int step = idx >> 11;
    int co = m0 * 16 + (lane & 15);
    int kg = step * 32 + ((lane >> 4) << 3) + j;
    int kk = kg >> 6;
    int c  = kg & 63;
    wA[idx] = (short)f2bf(w[(co * 64 + c) * 9 + kk]);
}

__global__ __launch_bounds__(256, 4) void dcn_fwd(const unsigned short* __restrict__ xt,
                                                  const float* __restrict__ offset,
                                                  const float* __restrict__ mask,
                                                  const short* __restrict__ wA,
                                                  float* __restrict__ out) {
    int bid = blockIdx.x;
    int swz = (bid & 7) * 144 + (bid >> 3);   // bijective XCD swizzle (1152 = 8*144)

    int wave = threadIdx.x >> 6;
    int lane = threadIdx.x & 63;
    int l15  = lane & 15;
    int lg   = lane >> 4;

    int n    = swz / 144;
    int prem = (swz % 144) * 64 + wave * 16;
    int ho   = prem / 96;
    int wo0  = prem % 96;
    int wo   = wo0 + l15;

    const unsigned short* xn = xt + (size_t)n * HWX * 64;

    f32x4 acc[4] = {f32x4{0,0,0,0}, f32x4{0,0,0,0}, f32x4{0,0,0,0}, f32x4{0,0,0,0}};

    #pragma unroll
    for (int kk = 0; kk < 9; ++kk) {
        int ky = kk / 3, kx = kk % 3;
        float dy = offset[((n * 18 + 2 * kk + 0) * 96 + ho) * 96 + wo];
        float dx = offset[((n * 18 + 2 * kk + 1) * 96 + ho) * 96 + wo];
        float m  = mask[((n * 9 + kk) * 96 + ho) * 96 + wo];

        float py = dy + (float)(ky + ho - 1);
        float px = dx + (float)(kx + wo - 1);
        float y0f = floorf(py), x0f = floorf(px);
        float wy1 = py - y0f,  wx1 = px - x0f;
        float wy0 = 1.f - wy1, wx0 = 1.f - wx1;
        int y0 = (int)y0f, x0 = (int)x0f;
        int y1 = y0 + 1,   x1 = x0 + 1;
        bool vy0 = (y0 >= 0) && (y0 < 96);
        bool vy1 = (y1 >= 0) && (y1 < 96);
        bool vx0 = (x0 >= 0) && (x0 < 96);
        bool vx1 = (x1 >= 0) && (x1 < 96);
        int y0c = min(max(y0, 0), 95), y1c = min(max(y1, 0), 95);
        int x0c = min(max(x0, 0), 95), x1c = min(max(x1, 0), 95);
        float w00 = wy0 * wx0 * m * ((vy0 && vx0) ? 1.f : 0.f);
        float w01 = wy0 * wx1 * m * ((vy0 && vx1) ? 1.f : 0.f);
        float w10 = wy1 * wx0 * m * ((vy1 && vx0) ? 1.f : 0.f);
        float w11 = wy1 * wx1 * m * ((vy1 && vx1) ? 1.f : 0.f);
        int ib00 = (y0c * 96 + x0c) * 64;
        int ib01 = (y0c * 96 + x1c) * 64;
        int ib10 = (y1c * 96 + x0c) * 64;
        int ib11 = (y1c * 96 + x1c) * 64;

        #pragma unroll
        for (int half = 0; half < 2; ++half) {
            int step = kk * 2 + half;
            int cb   = half * 32 + lg * 8;   // lane's first channel; 4-lane group = one 64B line

            // weight A-fragments: 16B/lane coalesced, L1-hot
            const short8* wp = (const short8*)wA + step * 256 + lane;
            short8 af0 = wp[0];
            short8 af1 = wp[64];
            short8 af2 = wp[128];
            short8 af3 = wp[192];

            // one 16B bf16 load per corner (8 channels)
            u32x4 u00, u01, u10, u11;
            { short8 q = *(const short8*)(xn + ib00 + cb); u00 = *(u32x4*)&q; }
            { short8 q = *(const short8*)(xn + ib01 + cb); u01 = *(u32x4*)&q; }
            { short8 q = *(const short8*)(xn + ib10 + cb); u10 = *(u32x4*)&q; }
            { short8 q = *(const short8*)(xn + ib11 + cb); u11 = *(u32x4*)&q; }

            u32x4 bu;
            #pragma unroll
            for (int p = 0; p < 4; ++p) {
                float v00l = u2f(u00[p] << 16), v00h = u2f(u00[p] & 0xffff0000u);
                float v01l = u2f(u01[p] << 16), v01h = u2f(u01[p] & 0xffff0000u);
                float v10l = u2f(u10[p] << 16), v10h = u2f(u10[p] & 0xffff0000u);
                float v11l = u2f(u11[p] << 16), v11h = u2f(u11[p] & 0xffff0000u);
                float slo = w00 * v00l + w01 * v01l + w10 * v10l + w11 * v11l;
                float shi = w00 * v00h + w01 * v01h + w10 * v10h + w11 * v11h;
                bu[p] = pack2bf(slo, shi);
            }
            short8 bfrag = *(short8*)&bu;

            acc[0] = __builtin_amdgcn_mfma_f32_16x16x32_bf16(af0, bfrag, acc[0], 0, 0, 0);
            acc[1] = __builtin_amdgcn_mfma_f32_16x16x32_bf16(af1, bfrag, acc[1], 0, 0, 0);
            acc[2] = __builtin_amdgcn_mfma_f32_16x16x32_bf16(af2, bfrag, acc[2], 0, 0, 0);
            acc[3] = __builtin_amdgcn_mfma_f32_16x16x32_bf16(af3, bfrag, acc[3], 0, 0, 0);
        }
    }

    // D: lane l, reg r -> co = m0*16 + lg*4 + r, pixel col = l15
    size_t obase = (size_t)n * COUT * HWX + (size_t)ho * 96 + wo;
    #pragma unroll
    for (int m0 = 0; m0 < 4; ++m0) {
        #pragma unroll
        for (int r = 0; r < 4; ++r) {
            int co = m0 * 16 + lg * 4 + r;
            out[obase + (size_t)co * HWX] = acc[m0][r];
        }
    }
}

extern "C" void kernel_launch(void* const* d_in, const int* in_sizes, int n_in,
                              void* d_out, int out_size, void* d_ws, size_t ws_size,
                              hipStream_t stream) {
    const float* x      = (const float*)d_in[0];
    const float* offset = (const float*)d_in[1];
    const float* mask   = (const float*)d_in[2];
    const float* w      = (const float*)d_in[3];
    float* out = (float*)d_out;
    unsigned* xt = (unsigned*)d_ws;                                   // 8*9216*64*2 = 9,437,184 B
    short* wA    = (short*)((char*)d_ws + (size_t)8 * HWX * 64 * 2);  // +73,728 B

    hipLaunchKernelGGL(nchw_to_nhwc_bf16, dim3(1152), dim3(256), 0, stream, x, xt);
    hipLaunchKernelGGL(dcn_prep_weight, dim3(144), dim3(256), 0, stream, w, wA);
    hipLaunchKernelGGL(dcn_fwd, dim3(1152), dim3(256), 0, stream,
                       (const unsigned short*)xt, offset, mask, wA, out);
}